// Round 1
// baseline (352.069 us; speedup 1.0000x reference)
//
#include <hip/hip_runtime.h>
#include <hip/hip_bf16.h>

#define N_NODES 50000
#define N_EDGES 800000
#define E_TOT 850000  // edges + self loops, CSR-resident
#define F_IN 32
#define CELL_DIM 16
#define D_IN 48      // F_IN + CELL_DIM
#define X_STRIDE 33  // F_IN + 1 (cell id column)
#define NUM_CELLS 854
#define NEG_SLOPE 0.2f
#define SCAN_BLOCKS 49     // ceil(50000/1024)
#define NODE0_BLOCKS 2048  // persistent node0 blocks (8 nodes per block-iteration)
#define HIST_BLOCKS 3125   // ceil(800000/256)
#define AGG_BATCH 24       // single predicated gather batch; deg ~17±4 -> 97% one batch

typedef unsigned int uint;
typedef unsigned short ushort;

// f32 -> bf16 bits, round-to-nearest-even
static __device__ __forceinline__ uint f2b(float f) {
  uint x = __float_as_uint(f);
  return (x + 0x7fffu + ((x >> 16) & 1u)) >> 16;
}
static __device__ __forceinline__ float b2f_lo(uint w) { return __uint_as_float(w << 16); }
static __device__ __forceinline__ float b2f_hi(uint w) { return __uint_as_float(w & 0xffff0000u); }
static __device__ __forceinline__ float lrelu(float e) { return e > 0.f ? e : NEG_SLOPE * e; }

// ---------------- Fused node0 + degree histogram ----------------
// node0 part: block = 4 waves = 8 nodes/iteration. Wave w: head h=w&1, node-quad q=w>>1.
// Lane l holds W0 column W0[k][h*64+l] in 48 VGPRs (no spill). Input rows staged in LDS
// by each wave (2 rows), read back as wave-uniform float4 broadcasts (no shfl chains).

__global__ __launch_bounds__(256) void k_node0h(const float* __restrict__ x,
                                                const float* __restrict__ emb,
                                                const float* __restrict__ W0,
                                                const float* __restrict__ asrc,
                                                const float* __restrict__ adst,
                                                const int* __restrict__ ei,
                                                ushort* __restrict__ h0u,
                                                float* __restrict__ as0, float* __restrict__ ad0,
                                                int* __restrict__ deg) {
  int tid = threadIdx.x;
  if (blockIdx.x >= NODE0_BLOCKS) {  // histogram part
    int e = (blockIdx.x - NODE0_BLOCKS) * 256 + tid;
    if (e < N_EDGES) atomicAdd(&deg[ei[N_EDGES + e]], 1);
    return;
  }
  __shared__ float hin[8][48];  // 8 node rows; float4 reads are wave-uniform (broadcast)
  int lane = tid & 63, wid = tid >> 6;
  int h = wid & 1;       // head
  int q = wid >> 1;      // node-quad (0: nodes 0-3, 1: nodes 4-7)
  float w0r[D_IN];       // 48 VGPRs: this head's W0 column for channel `lane`
#pragma unroll
  for (int k = 0; k < D_IN; ++k) w0r[k] = W0[k * 128 + h * 64 + lane];
  float av_s = asrc[h * 64 + lane], av_d = adst[h * 64 + lane];

  for (int g = blockIdx.x; g < N_NODES / 8; g += NODE0_BLOCKS) {
    int nb = g * 8;
    // stage: wave w stages rows 2w, 2w+1
#pragma unroll
    for (int j = 0; j < 2; ++j) {
      int loc = 2 * wid + j;
      int n = nb + loc;
      float t = 0.f;
      if (lane < 33) t = x[n * X_STRIDE + lane];
      int cid = (int)__shfl(t, 32, 64);
      cid = cid < 0 ? 0 : (cid >= NUM_CELLS ? NUM_CELLS - 1 : cid);  // fault guard
      if (lane >= 32 && lane < 48) t = emb[cid * CELL_DIM + (lane - 32)];
      if (lane < 48) hin[loc][lane] = t;
    }
    __syncthreads();
    // compute: 4 nodes of my quad, my head, channel = lane
#pragma unroll
    for (int j = 0; j < 4; ++j) {
      int loc = 4 * q + j;
      int n = nb + loc;
      const float4* hp = (const float4*)hin[loc];
      float acc = 0.f;
#pragma unroll
      for (int k4 = 0; k4 < 12; ++k4) {
        float4 hh = hp[k4];
        acc = fmaf(hh.x, w0r[4 * k4 + 0], acc);
        acc = fmaf(hh.y, w0r[4 * k4 + 1], acc);
        acc = fmaf(hh.z, w0r[4 * k4 + 2], acc);
        acc = fmaf(hh.w, w0r[4 * k4 + 3], acc);
      }
      h0u[(n * 64 + lane) * 2 + h] = (ushort)f2b(acc);  // packed half of the bf16x2 word
      float sa = acc * av_s, sd = acc * av_d;
#pragma unroll
      for (int o = 32; o >= 1; o >>= 1) {
        sa += __shfl_xor(sa, o, 64);
        sd += __shfl_xor(sd, o, 64);
      }
      if (lane == 0) {
        as0[n * 2 + h] = sa;
        ad0[n * 2 + h] = sd;
      }
    }
    __syncthreads();  // before restaging
  }
}

// ---------------- CSR scans ----------------

__global__ __launch_bounds__(1024) void k_scan1(const int* __restrict__ deg, int* __restrict__ off,
                                                int* __restrict__ bsum) {
  __shared__ int ws[16];
  int tid = threadIdx.x;
  int lane = tid & 63, wid = tid >> 6;
  int i = blockIdx.x * 1024 + tid;
  int v = (i < N_NODES) ? deg[i] + 1 : 0;  // +1 slot for self-loop
  int sc = v;
#pragma unroll
  for (int o = 1; o < 64; o <<= 1) {
    int t = __shfl_up(sc, o, 64);
    if (lane >= o) sc += t;
  }
  if (lane == 63) ws[wid] = sc;
  __syncthreads();
  if (tid < 16) {
    int w = ws[tid];
    int s = w;
#pragma unroll
    for (int o = 1; o < 16; o <<= 1) {
      int t = __shfl_up(s, o, 64);
      if (tid >= o) s += t;
    }
    ws[tid] = s - w;  // exclusive wave prefix
  }
  __syncthreads();
  int excl = sc - v + ws[wid];
  if (i < N_NODES) off[i] = excl;
  if (tid == 1023) bsum[blockIdx.x] = excl + v;  // block total
}

__global__ __launch_bounds__(1024) void k_scan23(int* __restrict__ off, int* __restrict__ ofs,
                                                 const int* __restrict__ bsum) {
  __shared__ int carry_s;
  int tid = threadIdx.x;
  if (tid < 64) {
    int v = (tid < SCAN_BLOCKS) ? bsum[tid] : 0;
    int s = v;
#pragma unroll
    for (int o = 1; o < 64; o <<= 1) {
      int t = __shfl_up(s, o, 64);
      if (tid >= o) s += t;
    }
    if (tid == (int)blockIdx.x) carry_s = s - v;  // exclusive prefix of this block
  }
  __syncthreads();
  int carry = carry_s;
  int i = blockIdx.x * 1024 + tid;
  if (i < N_NODES) {
    int v = off[i] + carry;
    off[i] = v;
    ofs[i] = v;
  }
  if (i == 0) off[N_NODES] = E_TOT;
}

// scatter edges into CSR slots + compute layer-0 attention weights; tail fills self-loops
__global__ __launch_bounds__(256) void k_scatter(const int* __restrict__ ei, int* __restrict__ ofs,
                                                 const int* __restrict__ off,
                                                 const float2* __restrict__ as0v,
                                                 const float2* __restrict__ ad0v,
                                                 uint2* __restrict__ ew) {
  int t = blockIdx.x * 256 + threadIdx.x;
  if (t < N_EDGES) {
    int s = ei[t], d = ei[N_EDGES + t];
    float2 a_s = as0v[s], a_d = ad0v[d];
    float w0 = __expf(lrelu(a_s.x + a_d.x));
    float w1 = __expf(lrelu(a_s.y + a_d.y));
    int p = atomicAdd(&ofs[d], 1);
    ew[p] = make_uint2((uint)s, f2b(w0) | (f2b(w1) << 16));
  } else if (t < N_EDGES + N_NODES) {
    int n = t - N_EDGES;  // self-loop record in the reserved last slot
    int slot = off[n + 1] - 1;
    float2 a_s = as0v[n], a_d = ad0v[n];
    float w0 = __expf(lrelu(a_s.x + a_d.x));
    float w1 = __expf(lrelu(a_s.y + a_d.y));
    ew[slot] = make_uint2((uint)n, f2b(w0) | (f2b(w1) << 16));
  }
}

// ---------------- Fused aggregate L0 (+LN+ELU+linear1+alpha1) ----------------
// R11: single 24-edge predicated batch anchored at i1 (deg ~17+-4 => ~97% of nodes finish
// in ONE s_load->gather latency round instead of ~2.1). Records are loaded contiguously
// (merges to s_load_dwordx16); out-of-range slots get weight forced to 0 (exact zero
// contribution; den>0 guaranteed by self-loop) and their gather redirected to ew[i0].x so
// padded gathers hit an already-needed line. All predication is uniform => SALU. Gather
// address is SGPR-base + (lane<<2): zero per-edge address VALU.

__global__ __launch_bounds__(256) void k_agg0(const int* __restrict__ off,
                                              const uint2* __restrict__ ew,
                                              const uint* __restrict__ h0p,
                                              const float* __restrict__ b0,
                                              const float* __restrict__ lng,
                                              const float* __restrict__ lnb,
                                              const float* __restrict__ W1,
                                              const float* __restrict__ asrc1,
                                              const float* __restrict__ adst1,
                                              ushort* __restrict__ h1b,
                                              float* __restrict__ as1, float* __restrict__ ad1) {
  int n = blockIdx.x * 4 + (threadIdx.x >> 6);
  int lane = threadIdx.x & 63;
  float acc0 = 0.f, acc1 = 0.f, den0 = 0.f, den1 = 0.f;
  int i0 = off[n], i1 = off[n + 1];
  int cnt = i1 - i0;             // >= 1 (self-loop)
  int nbat = (cnt + AGG_BATCH - 1) / AGG_BATCH;
  uint safe_x = ew[i0].x;        // always-valid source for padded slots

  for (int b = 0; b < nbat; ++b) {
    int base = i1 - (nbat - b) * AGG_BATCH;
    if (base < 0) base = 0;      // only first batch of low-index nodes clamps
    uint sx[AGG_BATCH], wy[AGG_BATCH];
#pragma unroll
    for (int j = 0; j < AGG_BATCH; ++j) {
      uint2 r = ew[base + j];    // contiguous uniform loads -> s_load_dwordx16
      bool valid = (base + j >= i0) && (base + j < i1);
      sx[j] = valid ? r.x : safe_x;
      wy[j] = valid ? r.y : 0u;  // bf16x2 weight word; 0 kills both heads exactly
    }
    uint hh[AGG_BATCH];
#pragma unroll
    for (int j = 0; j < AGG_BATCH; ++j) hh[j] = h0p[sx[j] * 64 + lane];  // 24 gathers in flight
#pragma unroll
    for (int j = 0; j < AGG_BATCH; ++j) {
      float wl = b2f_lo(wy[j]), wh = b2f_hi(wy[j]);   // uniform -> SALU unpack
      acc0 = fmaf(wl, b2f_lo(hh[j]), acc0); den0 += wl;
      acc1 = fmaf(wh, b2f_hi(hh[j]), acc1); den1 += wh;
    }
  }

  float v = 0.5f * (acc0 / den0 + acc1 / den1) + b0[lane];
  // LayerNorm across the 64 channels (one wave)
  float mu = v;
#pragma unroll
  for (int o = 32; o >= 1; o >>= 1) mu += __shfl_xor(mu, o, 64);
  mu *= (1.0f / 64.0f);
  float d = v - mu;
  float vr = d * d;
#pragma unroll
  for (int o = 32; o >= 1; o >>= 1) vr += __shfl_xor(vr, o, 64);
  vr *= (1.0f / 64.0f);
  float y = d * rsqrtf(vr + 1e-5f) * lng[lane] + lnb[lane];
  // ELU
  y = y > 0.f ? y : expm1f(y);
  // linear1: h1[c] = sum_k y_k * W1[k,c]
  float h1v = 0.f;
#pragma unroll
  for (int k = 0; k < 64; ++k) {
    float yk = __shfl(y, k, 64);
    h1v += yk * W1[k * 64 + lane];
  }
  h1b[n * 64 + lane] = (ushort)f2b(h1v);
  float sa = h1v * asrc1[lane];
  float sdv = h1v * adst1[lane];
#pragma unroll
  for (int o = 32; o >= 1; o >>= 1) {
    sa += __shfl_xor(sa, o, 64);
    sdv += __shfl_xor(sdv, o, 64);
  }
  if (lane == 0) {
    as1[n] = sa;
    ad1[n] = sdv;
  }
}

// ---------------- Layer 1 aggregate -> output ----------------
// Same single-batch predicated structure; as1 gathers are scalar loads (uniform index),
// weights computed per-lane then zeroed for padded slots.

__global__ __launch_bounds__(256) void k_agg1(const int* __restrict__ off,
                                              const uint2* __restrict__ ew,
                                              const ushort* __restrict__ h1b,
                                              const float* __restrict__ as1,
                                              const float* __restrict__ ad1,
                                              const float* __restrict__ b1,
                                              float* __restrict__ out) {
  int n = blockIdx.x * 4 + (threadIdx.x >> 6);
  int lane = threadIdx.x & 63;
  float adv = ad1[n];
  float acc = 0.f, den = 0.f;
  int i0 = off[n], i1 = off[n + 1];
  int cnt = i1 - i0;
  int nbat = (cnt + AGG_BATCH - 1) / AGG_BATCH;
  uint safe_x = ew[i0].x;

  for (int b = 0; b < nbat; ++b) {
    int base = i1 - (nbat - b) * AGG_BATCH;
    if (base < 0) base = 0;
    uint sx[AGG_BATCH];
#pragma unroll
    for (int j = 0; j < AGG_BATCH; ++j) {
      uint2 r = ew[base + j];
      bool valid = (base + j >= i0) && (base + j < i1);
      sx[j] = valid ? r.x : safe_x;
    }
    float av[AGG_BATCH];
#pragma unroll
    for (int j = 0; j < AGG_BATCH; ++j) av[j] = as1[sx[j]];       // scalar loads (uniform)
    ushort hh[AGG_BATCH];
#pragma unroll
    for (int j = 0; j < AGG_BATCH; ++j) hh[j] = h1b[sx[j] * 64 + lane];
#pragma unroll
    for (int j = 0; j < AGG_BATCH; ++j) {
      float w = __expf(lrelu(av[j] + adv));
      bool valid = (base + j >= i0) && (base + j < i1);
      w = valid ? w : 0.f;                                        // uniform cndmask
      acc = fmaf(w, __uint_as_float((uint)hh[j] << 16), acc);
      den += w;
    }
  }
  out[n * 64 + lane] = acc / den + b1[lane];
}

// ---------------- host ----------------

extern "C" void kernel_launch(void* const* d_in, const int* in_sizes, int n_in,
                              void* d_out, int out_size, void* d_ws, size_t ws_size,
                              hipStream_t stream) {
  const float* x    = (const float*)d_in[0];
  const int*   ei   = (const int*)d_in[1];
  const float* emb  = (const float*)d_in[2];
  const float* W0   = (const float*)d_in[3];
  const float* as0w = (const float*)d_in[4];
  const float* ad0w = (const float*)d_in[5];
  const float* b0   = (const float*)d_in[6];
  const float* lng  = (const float*)d_in[7];
  const float* lnb  = (const float*)d_in[8];
  const float* W1   = (const float*)d_in[9];
  const float* as1w = (const float*)d_in[10];
  const float* ad1w = (const float*)d_in[11];
  const float* b1   = (const float*)d_in[12];
  float* out = (float*)d_out;

  // workspace layout (8B-aligned arrays first); total ~29 MB
  uint2* ew  = (uint2*)d_ws;                  // E_TOT {src, bf16x2 w0|w1}
  float* as0 = (float*)(ew + E_TOT);          // N*2
  float* ad0 = as0 + N_NODES * 2;             // N*2
  float* as1 = ad0 + N_NODES * 2;             // N
  float* ad1 = as1 + N_NODES;                 // N
  uint* h0p = (uint*)(ad1 + N_NODES);         // N*64 (bf16x2 packed; written as ushort halves)
  ushort* h1b = (ushort*)(h0p + N_NODES * 64);  // N*64 bf16
  int* deg  = (int*)(h1b + N_NODES * 64);     // N
  int* off  = deg + N_NODES;                  // N+1
  int* ofs  = off + N_NODES + 1;              // N
  int* bsum = ofs + N_NODES;                  // 64

  hipMemsetAsync(deg, 0, N_NODES * sizeof(int), stream);
  k_node0h<<<NODE0_BLOCKS + HIST_BLOCKS, 256, 0, stream>>>(x, emb, W0, as0w, ad0w, ei,
                                                           (ushort*)h0p, as0, ad0, deg);
  k_scan1<<<SCAN_BLOCKS, 1024, 0, stream>>>(deg, off, bsum);
  k_scan23<<<SCAN_BLOCKS, 1024, 0, stream>>>(off, ofs, bsum);
  k_scatter<<<(N_EDGES + N_NODES + 255) / 256, 256, 0, stream>>>(ei, ofs, off, (const float2*)as0,
                                                                 (const float2*)ad0, ew);
  k_agg0<<<N_NODES / 4, 256, 0, stream>>>(off, ew, h0p, b0, lng, lnb, W1, as1w, ad1w,
                                          h1b, as1, ad1);
  k_agg1<<<N_NODES / 4, 256, 0, stream>>>(off, ew, h1b, as1, ad1, b1, out);
}

// Round 3
// 313.372 us; speedup vs baseline: 1.1235x; 1.1235x over previous
//
#include <hip/hip_runtime.h>
#include <hip/hip_bf16.h>

#define N_NODES 50000
#define N_EDGES 800000
#define E_TOT 850000  // edges + self loops, CSR-resident
#define F_IN 32
#define CELL_DIM 16
#define D_IN 48      // F_IN + CELL_DIM
#define X_STRIDE 33  // F_IN + 1 (cell id column)
#define NUM_CELLS 854
#define NEG_SLOPE 0.2f
#define SCAN_BLOCKS 49     // ceil(50000/1024)
#define NODE0_BLOCKS 2048  // persistent node0 blocks (8 nodes per block-iteration)
#define HIST_BLOCKS 3125   // ceil(800000/256)

typedef unsigned int uint;
typedef unsigned short ushort;

// f32 -> bf16 bits, round-to-nearest-even
static __device__ __forceinline__ uint f2b(float f) {
  uint x = __float_as_uint(f);
  return (x + 0x7fffu + ((x >> 16) & 1u)) >> 16;
}
static __device__ __forceinline__ float b2f_lo(uint w) { return __uint_as_float(w << 16); }
static __device__ __forceinline__ float b2f_hi(uint w) { return __uint_as_float(w & 0xffff0000u); }
static __device__ __forceinline__ float lrelu(float e) { return e > 0.f ? e : NEG_SLOPE * e; }

// ---------------- Fused node0 + degree histogram (unchanged, known-good) ----------------

__global__ __launch_bounds__(256) void k_node0h(const float* __restrict__ x,
                                                const float* __restrict__ emb,
                                                const float* __restrict__ W0,
                                                const float* __restrict__ asrc,
                                                const float* __restrict__ adst,
                                                const int* __restrict__ ei,
                                                ushort* __restrict__ h0u,
                                                float* __restrict__ as0, float* __restrict__ ad0,
                                                int* __restrict__ deg) {
  int tid = threadIdx.x;
  if (blockIdx.x >= NODE0_BLOCKS) {  // histogram part
    int e = (blockIdx.x - NODE0_BLOCKS) * 256 + tid;
    if (e < N_EDGES) atomicAdd(&deg[ei[N_EDGES + e]], 1);
    return;
  }
  __shared__ float hin[8][48];  // 8 node rows; float4 reads are wave-uniform (broadcast)
  int lane = tid & 63, wid = tid >> 6;
  int h = wid & 1;       // head
  int q = wid >> 1;      // node-quad
  float w0r[D_IN];       // 48 VGPRs: this head's W0 column for channel `lane`
#pragma unroll
  for (int k = 0; k < D_IN; ++k) w0r[k] = W0[k * 128 + h * 64 + lane];
  float av_s = asrc[h * 64 + lane], av_d = adst[h * 64 + lane];

  for (int g = blockIdx.x; g < N_NODES / 8; g += NODE0_BLOCKS) {
    int nb = g * 8;
#pragma unroll
    for (int j = 0; j < 2; ++j) {
      int loc = 2 * wid + j;
      int n = nb + loc;
      float t = 0.f;
      if (lane < 33) t = x[n * X_STRIDE + lane];
      int cid = (int)__shfl(t, 32, 64);
      cid = cid < 0 ? 0 : (cid >= NUM_CELLS ? NUM_CELLS - 1 : cid);  // fault guard
      if (lane >= 32 && lane < 48) t = emb[cid * CELL_DIM + (lane - 32)];
      if (lane < 48) hin[loc][lane] = t;
    }
    __syncthreads();
#pragma unroll
    for (int j = 0; j < 4; ++j) {
      int loc = 4 * q + j;
      int n = nb + loc;
      const float4* hp = (const float4*)hin[loc];
      float acc = 0.f;
#pragma unroll
      for (int k4 = 0; k4 < 12; ++k4) {
        float4 hh = hp[k4];
        acc = fmaf(hh.x, w0r[4 * k4 + 0], acc);
        acc = fmaf(hh.y, w0r[4 * k4 + 1], acc);
        acc = fmaf(hh.z, w0r[4 * k4 + 2], acc);
        acc = fmaf(hh.w, w0r[4 * k4 + 3], acc);
      }
      h0u[(n * 64 + lane) * 2 + h] = (ushort)f2b(acc);  // packed half of the bf16x2 word
      float sa = acc * av_s, sd = acc * av_d;
#pragma unroll
      for (int o = 32; o >= 1; o >>= 1) {
        sa += __shfl_xor(sa, o, 64);
        sd += __shfl_xor(sd, o, 64);
      }
      if (lane == 0) {
        as0[n * 2 + h] = sa;
        ad0[n * 2 + h] = sd;
      }
    }
    __syncthreads();  // before restaging
  }
}

// ---------------- CSR scans (unchanged) ----------------

__global__ __launch_bounds__(1024) void k_scan1(const int* __restrict__ deg, int* __restrict__ off,
                                                int* __restrict__ bsum) {
  __shared__ int ws[16];
  int tid = threadIdx.x;
  int lane = tid & 63, wid = tid >> 6;
  int i = blockIdx.x * 1024 + tid;
  int v = (i < N_NODES) ? deg[i] + 1 : 0;  // +1 slot for self-loop
  int sc = v;
#pragma unroll
  for (int o = 1; o < 64; o <<= 1) {
    int t = __shfl_up(sc, o, 64);
    if (lane >= o) sc += t;
  }
  if (lane == 63) ws[wid] = sc;
  __syncthreads();
  if (tid < 16) {
    int w = ws[tid];
    int s = w;
#pragma unroll
    for (int o = 1; o < 16; o <<= 1) {
      int t = __shfl_up(s, o, 64);
      if (tid >= o) s += t;
    }
    ws[tid] = s - w;  // exclusive wave prefix
  }
  __syncthreads();
  int excl = sc - v + ws[wid];
  if (i < N_NODES) off[i] = excl;
  if (tid == 1023) bsum[blockIdx.x] = excl + v;  // block total
}

__global__ __launch_bounds__(1024) void k_scan23(int* __restrict__ off, int* __restrict__ ofs,
                                                 const int* __restrict__ bsum) {
  __shared__ int carry_s;
  int tid = threadIdx.x;
  if (tid < 64) {
    int v = (tid < SCAN_BLOCKS) ? bsum[tid] : 0;
    int s = v;
#pragma unroll
    for (int o = 1; o < 64; o <<= 1) {
      int t = __shfl_up(s, o, 64);
      if (tid >= o) s += t;
    }
    if (tid == (int)blockIdx.x) carry_s = s - v;  // exclusive prefix of this block
  }
  __syncthreads();
  int carry = carry_s;
  int i = blockIdx.x * 1024 + tid;
  if (i < N_NODES) {
    int v = off[i] + carry;
    off[i] = v;
    ofs[i] = v;
  }
  if (i == 0) off[N_NODES] = E_TOT;
}

// scatter edges into CSR slots + compute layer-0 attention weights (unchanged)
__global__ __launch_bounds__(256) void k_scatter(const int* __restrict__ ei, int* __restrict__ ofs,
                                                 const int* __restrict__ off,
                                                 const float2* __restrict__ as0v,
                                                 const float2* __restrict__ ad0v,
                                                 uint2* __restrict__ ew) {
  int t = blockIdx.x * 256 + threadIdx.x;
  if (t < N_EDGES) {
    int s = ei[t], d = ei[N_EDGES + t];
    float2 a_s = as0v[s], a_d = ad0v[d];
    float w0 = __expf(lrelu(a_s.x + a_d.x));
    float w1 = __expf(lrelu(a_s.y + a_d.y));
    int p = atomicAdd(&ofs[d], 1);
    ew[p] = make_uint2((uint)s, f2b(w0) | (f2b(w1) << 16));
  } else if (t < N_EDGES + N_NODES) {
    int n = t - N_EDGES;  // self-loop record in the reserved last slot
    int slot = off[n + 1] - 1;
    float2 a_s = as0v[n], a_d = ad0v[n];
    float w0 = __expf(lrelu(a_s.x + a_d.x));
    float w1 = __expf(lrelu(a_s.y + a_d.y));
    ew[slot] = make_uint2((uint)n, f2b(w0) | (f2b(w1) << 16));
  }
}

// ---------------- Fused aggregate L0 (+LN+ELU+linear1+alpha1) ----------------
// R13: 2 waves per node (512-thread block, 4 nodes/block). Each wave aggregates half the
// node's edge list with the R10 8/4/1 ladder (VGPR ~32 preserved -> no occupancy cliff);
// partials combine via LDS + one barrier. Epilogue on wave A only. linear1 switched from
// 64x ds_bpermute + serial fma chain to LDS-staged y + 16 uniform float4 broadcasts with
// 4 partial accumulators (breaks the 64-deep serial dependency).

__global__ __launch_bounds__(512) void k_agg0(const int* __restrict__ off,
                                              const uint2* __restrict__ ew,
                                              const uint* __restrict__ h0p,
                                              const float* __restrict__ b0,
                                              const float* __restrict__ lng,
                                              const float* __restrict__ lnb,
                                              const float* __restrict__ W1,
                                              const float* __restrict__ asrc1,
                                              const float* __restrict__ adst1,
                                              ushort* __restrict__ h1b,
                                              float* __restrict__ as1, float* __restrict__ ad1) {
  __shared__ float part[4][4][64];  // [node][acc0,acc1,den0,den1][lane] — written by half B
  __shared__ float yb[4][64];       // staged y for linear1 broadcasts
  int tid = threadIdx.x;
  int lane = tid & 63, wid = tid >> 6;
  int nl = wid >> 1;    // node-local 0..3
  int half = wid & 1;   // which half of the edge list
  int n = blockIdx.x * 4 + nl;
  float acc0 = 0.f, acc1 = 0.f, den0 = 0.f, den1 = 0.f;
  int i0 = off[n], i1 = off[n + 1];
  int mid = i0 + ((i1 - i0 + 1) >> 1);
  int lo = half ? mid : i0;
  int hi = half ? i1 : mid;
  int i = lo;
  for (; i + 7 < hi; i += 8) {
    uint2 r[8];
    uint h[8];
#pragma unroll
    for (int j = 0; j < 8; ++j) r[j] = ew[i + j];
#pragma unroll
    for (int j = 0; j < 8; ++j) h[j] = h0p[r[j].x * 64 + lane];
#pragma unroll
    for (int j = 0; j < 8; ++j) {
      float w;
      w = b2f_lo(r[j].y); acc0 += w * b2f_lo(h[j]); den0 += w;
      w = b2f_hi(r[j].y); acc1 += w * b2f_hi(h[j]); den1 += w;
    }
  }
  for (; i + 3 < hi; i += 4) {
    uint2 r[4];
    uint h[4];
#pragma unroll
    for (int j = 0; j < 4; ++j) r[j] = ew[i + j];
#pragma unroll
    for (int j = 0; j < 4; ++j) h[j] = h0p[r[j].x * 64 + lane];
#pragma unroll
    for (int j = 0; j < 4; ++j) {
      float w;
      w = b2f_lo(r[j].y); acc0 += w * b2f_lo(h[j]); den0 += w;
      w = b2f_hi(r[j].y); acc1 += w * b2f_hi(h[j]); den1 += w;
    }
  }
  for (; i < hi; ++i) {
    uint2 r = ew[i];
    uint h = h0p[r.x * 64 + lane];
    float w;
    w = b2f_lo(r.y); acc0 += w * b2f_lo(h); den0 += w;
    w = b2f_hi(r.y); acc1 += w * b2f_hi(h); den1 += w;
  }
  if (half) {
    part[nl][0][lane] = acc0;
    part[nl][1][lane] = acc1;
    part[nl][2][lane] = den0;
    part[nl][3][lane] = den1;
  }
  __syncthreads();
  if (half) return;  // barrier already passed by all threads
  acc0 += part[nl][0][lane];
  acc1 += part[nl][1][lane];
  den0 += part[nl][2][lane];
  den1 += part[nl][3][lane];

  float v = 0.5f * (acc0 / den0 + acc1 / den1) + b0[lane];
  // LayerNorm across the 64 channels (one wave)
  float mu = v;
#pragma unroll
  for (int o = 32; o >= 1; o >>= 1) mu += __shfl_xor(mu, o, 64);
  mu *= (1.0f / 64.0f);
  float d = v - mu;
  float vr = d * d;
#pragma unroll
  for (int o = 32; o >= 1; o >>= 1) vr += __shfl_xor(vr, o, 64);
  vr *= (1.0f / 64.0f);
  float y = d * rsqrtf(vr + 1e-5f) * lng[lane] + lnb[lane];
  y = y > 0.f ? y : expm1f(y);  // ELU
  // linear1 via LDS broadcasts: h1[c] = sum_k y_k * W1[k,c], 4 partial accumulators
  yb[nl][lane] = y;
  const float4* yp = (const float4*)yb[nl];  // wave-uniform reads (compiler inserts lgkmcnt)
  float p0 = 0.f, p1 = 0.f, p2 = 0.f, p3 = 0.f;
#pragma unroll
  for (int k4 = 0; k4 < 16; ++k4) {
    float4 yy = yp[k4];
    p0 = fmaf(yy.x, W1[(4 * k4 + 0) * 64 + lane], p0);
    p1 = fmaf(yy.y, W1[(4 * k4 + 1) * 64 + lane], p1);
    p2 = fmaf(yy.z, W1[(4 * k4 + 2) * 64 + lane], p2);
    p3 = fmaf(yy.w, W1[(4 * k4 + 3) * 64 + lane], p3);
  }
  float h1v = (p0 + p1) + (p2 + p3);
  h1b[n * 64 + lane] = (ushort)f2b(h1v);
  float sa = h1v * asrc1[lane];
  float sdv = h1v * adst1[lane];
#pragma unroll
  for (int o = 32; o >= 1; o >>= 1) {
    sa += __shfl_xor(sa, o, 64);
    sdv += __shfl_xor(sdv, o, 64);
  }
  if (lane == 0) {
    as1[n] = sa;
    ad1[n] = sdv;
  }
}

// ---------------- Layer 1 aggregate -> output ----------------
// R13: same 2-waves-per-node split; epilogue (divide+store) on wave A.

__global__ __launch_bounds__(512) void k_agg1(const int* __restrict__ off,
                                              const uint2* __restrict__ ew,
                                              const ushort* __restrict__ h1b,
                                              const float* __restrict__ as1,
                                              const float* __restrict__ ad1,
                                              const float* __restrict__ b1,
                                              float* __restrict__ out) {
  __shared__ float part[4][2][64];  // [node][acc,den][lane]
  int tid = threadIdx.x;
  int lane = tid & 63, wid = tid >> 6;
  int nl = wid >> 1;
  int half = wid & 1;
  int n = blockIdx.x * 4 + nl;
  float adv = ad1[n];
  float acc = 0.f, den = 0.f;
  int i0 = off[n], i1 = off[n + 1];
  int mid = i0 + ((i1 - i0 + 1) >> 1);
  int lo = half ? mid : i0;
  int hi = half ? i1 : mid;
  int i = lo;
  for (; i + 7 < hi; i += 8) {
    uint s[8];
    float a[8];
    uint h[8];
#pragma unroll
    for (int j = 0; j < 8; ++j) s[j] = ew[i + j].x;
#pragma unroll
    for (int j = 0; j < 8; ++j) a[j] = as1[s[j]];
#pragma unroll
    for (int j = 0; j < 8; ++j) h[j] = h1b[s[j] * 64 + lane];
#pragma unroll
    for (int j = 0; j < 8; ++j) {
      float w = __expf(lrelu(a[j] + adv));
      acc += w * __uint_as_float(h[j] << 16);
      den += w;
    }
  }
  for (; i + 3 < hi; i += 4) {
    uint s[4];
    float a[4];
    uint h[4];
#pragma unroll
    for (int j = 0; j < 4; ++j) s[j] = ew[i + j].x;
#pragma unroll
    for (int j = 0; j < 4; ++j) a[j] = as1[s[j]];
#pragma unroll
    for (int j = 0; j < 4; ++j) h[j] = h1b[s[j] * 64 + lane];
#pragma unroll
    for (int j = 0; j < 4; ++j) {
      float w = __expf(lrelu(a[j] + adv));
      acc += w * __uint_as_float(h[j] << 16);
      den += w;
    }
  }
  for (; i < hi; ++i) {
    uint s = ew[i].x;
    float w = __expf(lrelu(as1[s] + adv));
    acc += w * __uint_as_float((uint)h1b[s * 64 + lane] << 16);
    den += w;
  }
  if (half) {
    part[nl][0][lane] = acc;
    part[nl][1][lane] = den;
  }
  __syncthreads();
  if (half) return;
  acc += part[nl][0][lane];
  den += part[nl][1][lane];
  out[n * 64 + lane] = acc / den + b1[lane];
}

// ---------------- host ----------------

extern "C" void kernel_launch(void* const* d_in, const int* in_sizes, int n_in,
                              void* d_out, int out_size, void* d_ws, size_t ws_size,
                              hipStream_t stream) {
  const float* x    = (const float*)d_in[0];
  const int*   ei   = (const int*)d_in[1];
  const float* emb  = (const float*)d_in[2];
  const float* W0   = (const float*)d_in[3];
  const float* as0w = (const float*)d_in[4];
  const float* ad0w = (const float*)d_in[5];
  const float* b0   = (const float*)d_in[6];
  const float* lng  = (const float*)d_in[7];
  const float* lnb  = (const float*)d_in[8];
  const float* W1   = (const float*)d_in[9];
  const float* as1w = (const float*)d_in[10];
  const float* ad1w = (const float*)d_in[11];
  const float* b1   = (const float*)d_in[12];
  float* out = (float*)d_out;

  // workspace layout (8B-aligned arrays first); total ~29 MB
  uint2* ew  = (uint2*)d_ws;                  // E_TOT {src, bf16x2 w0|w1}
  float* as0 = (float*)(ew + E_TOT);          // N*2
  float* ad0 = as0 + N_NODES * 2;             // N*2
  float* as1 = ad0 + N_NODES * 2;             // N
  float* ad1 = as1 + N_NODES;                 // N
  uint* h0p = (uint*)(ad1 + N_NODES);         // N*64 (bf16x2 packed; written as ushort halves)
  ushort* h1b = (ushort*)(h0p + N_NODES * 64);  // N*64 bf16
  int* deg  = (int*)(h1b + N_NODES * 64);     // N
  int* off  = deg + N_NODES;                  // N+1
  int* ofs  = off + N_NODES + 1;              // N
  int* bsum = ofs + N_NODES;                  // 64

  hipMemsetAsync(deg, 0, N_NODES * sizeof(int), stream);
  k_node0h<<<NODE0_BLOCKS + HIST_BLOCKS, 256, 0, stream>>>(x, emb, W0, as0w, ad0w, ei,
                                                           (ushort*)h0p, as0, ad0, deg);
  k_scan1<<<SCAN_BLOCKS, 1024, 0, stream>>>(deg, off, bsum);
  k_scan23<<<SCAN_BLOCKS, 1024, 0, stream>>>(off, ofs, bsum);
  k_scatter<<<(N_EDGES + N_NODES + 255) / 256, 256, 0, stream>>>(ei, ofs, off, (const float2*)as0,
                                                                 (const float2*)ad0, ew);
  k_agg0<<<N_NODES / 4, 512, 0, stream>>>(off, ew, h0p, b0, lng, lnb, W1, as1w, ad1w,
                                          h1b, as1, ad1);
  k_agg1<<<N_NODES / 4, 512, 0, stream>>>(off, ew, h1b, as1, ad1, b1, out);
}

// Round 4
// 276.255 us; speedup vs baseline: 1.2744x; 1.1344x over previous
//
#include <hip/hip_runtime.h>
#include <hip/hip_bf16.h>

#define N_NODES 50000
#define N_EDGES 800000
#define E_TOT 850000  // edges + self loops, CSR-resident
#define F_IN 32
#define CELL_DIM 16
#define D_IN 48      // F_IN + CELL_DIM
#define X_STRIDE 33  // F_IN + 1 (cell id column)
#define NUM_CELLS 854
#define NEG_SLOPE 0.2f
#define SCAN_BLOCKS 49     // ceil(50000/1024)
#define NODE0_BLOCKS 2048  // persistent node0 blocks (8 nodes per block-iteration)
#define HIST_BLOCKS 3125   // ceil(800000/256)

typedef unsigned int uint;
typedef unsigned short ushort;

// f32 -> bf16 bits, round-to-nearest-even
static __device__ __forceinline__ uint f2b(float f) {
  uint x = __float_as_uint(f);
  return (x + 0x7fffu + ((x >> 16) & 1u)) >> 16;
}
static __device__ __forceinline__ float b2f_lo(uint w) { return __uint_as_float(w << 16); }
static __device__ __forceinline__ float b2f_hi(uint w) { return __uint_as_float(w & 0xffff0000u); }
static __device__ __forceinline__ float lrelu(float e) { return e > 0.f ? e : NEG_SLOPE * e; }

// ---------------- Fused node0 + degree histogram (unchanged, known-good) ----------------

__global__ __launch_bounds__(256) void k_node0h(const float* __restrict__ x,
                                                const float* __restrict__ emb,
                                                const float* __restrict__ W0,
                                                const float* __restrict__ asrc,
                                                const float* __restrict__ adst,
                                                const int* __restrict__ ei,
                                                ushort* __restrict__ h0u,
                                                float* __restrict__ as0, float* __restrict__ ad0,
                                                int* __restrict__ deg) {
  int tid = threadIdx.x;
  if (blockIdx.x >= NODE0_BLOCKS) {  // histogram part
    int e = (blockIdx.x - NODE0_BLOCKS) * 256 + tid;
    if (e < N_EDGES) atomicAdd(&deg[ei[N_EDGES + e]], 1);
    return;
  }
  __shared__ float hin[8][48];  // 8 node rows; float4 reads are wave-uniform (broadcast)
  int lane = tid & 63, wid = tid >> 6;
  int h = wid & 1;       // head
  int q = wid >> 1;      // node-quad (0: nodes 0-3, 1: nodes 4-7)
  float w0r[D_IN];       // 48 VGPRs: this head's W0 column for channel `lane`
#pragma unroll
  for (int k = 0; k < D_IN; ++k) w0r[k] = W0[k * 128 + h * 64 + lane];
  float av_s = asrc[h * 64 + lane], av_d = adst[h * 64 + lane];

  for (int g = blockIdx.x; g < N_NODES / 8; g += NODE0_BLOCKS) {
    int nb = g * 8;
    // stage: wave w stages rows 2w, 2w+1
#pragma unroll
    for (int j = 0; j < 2; ++j) {
      int loc = 2 * wid + j;
      int n = nb + loc;
      float t = 0.f;
      if (lane < 33) t = x[n * X_STRIDE + lane];
      int cid = (int)__shfl(t, 32, 64);
      cid = cid < 0 ? 0 : (cid >= NUM_CELLS ? NUM_CELLS - 1 : cid);  // fault guard
      if (lane >= 32 && lane < 48) t = emb[cid * CELL_DIM + (lane - 32)];
      if (lane < 48) hin[loc][lane] = t;
    }
    __syncthreads();
    // compute: 4 nodes of my quad, my head, channel = lane
#pragma unroll
    for (int j = 0; j < 4; ++j) {
      int loc = 4 * q + j;
      int n = nb + loc;
      const float4* hp = (const float4*)hin[loc];
      float acc = 0.f;
#pragma unroll
      for (int k4 = 0; k4 < 12; ++k4) {
        float4 hh = hp[k4];
        acc = fmaf(hh.x, w0r[4 * k4 + 0], acc);
        acc = fmaf(hh.y, w0r[4 * k4 + 1], acc);
        acc = fmaf(hh.z, w0r[4 * k4 + 2], acc);
        acc = fmaf(hh.w, w0r[4 * k4 + 3], acc);
      }
      h0u[(n * 64 + lane) * 2 + h] = (ushort)f2b(acc);  // packed half of the bf16x2 word
      float sa = acc * av_s, sd = acc * av_d;
#pragma unroll
      for (int o = 32; o >= 1; o >>= 1) {
        sa += __shfl_xor(sa, o, 64);
        sd += __shfl_xor(sd, o, 64);
      }
      if (lane == 0) {
        as0[n * 2 + h] = sa;
        ad0[n * 2 + h] = sd;
      }
    }
    __syncthreads();  // before restaging
  }
}

// ---------------- CSR scans (unchanged) ----------------

__global__ __launch_bounds__(1024) void k_scan1(const int* __restrict__ deg, int* __restrict__ off,
                                                int* __restrict__ bsum) {
  __shared__ int ws[16];
  int tid = threadIdx.x;
  int lane = tid & 63, wid = tid >> 6;
  int i = blockIdx.x * 1024 + tid;
  int v = (i < N_NODES) ? deg[i] + 1 : 0;  // +1 slot for self-loop
  int sc = v;
#pragma unroll
  for (int o = 1; o < 64; o <<= 1) {
    int t = __shfl_up(sc, o, 64);
    if (lane >= o) sc += t;
  }
  if (lane == 63) ws[wid] = sc;
  __syncthreads();
  if (tid < 16) {
    int w = ws[tid];
    int s = w;
#pragma unroll
    for (int o = 1; o < 16; o <<= 1) {
      int t = __shfl_up(s, o, 64);
      if (tid >= o) s += t;
    }
    ws[tid] = s - w;  // exclusive wave prefix
  }
  __syncthreads();
  int excl = sc - v + ws[wid];
  if (i < N_NODES) off[i] = excl;
  if (tid == 1023) bsum[blockIdx.x] = excl + v;  // block total
}

__global__ __launch_bounds__(1024) void k_scan23(int* __restrict__ off, int* __restrict__ ofs,
                                                 const int* __restrict__ bsum) {
  __shared__ int carry_s;
  int tid = threadIdx.x;
  if (tid < 64) {
    int v = (tid < SCAN_BLOCKS) ? bsum[tid] : 0;
    int s = v;
#pragma unroll
    for (int o = 1; o < 64; o <<= 1) {
      int t = __shfl_up(s, o, 64);
      if (tid >= o) s += t;
    }
    if (tid == (int)blockIdx.x) carry_s = s - v;  // exclusive prefix of this block
  }
  __syncthreads();
  int carry = carry_s;
  int i = blockIdx.x * 1024 + tid;
  if (i < N_NODES) {
    int v = off[i] + carry;
    off[i] = v;
    ofs[i] = v;
  }
  if (i == 0) off[N_NODES] = E_TOT;
}

// scatter edges into CSR slots + compute layer-0 attention weights (unchanged)
__global__ __launch_bounds__(256) void k_scatter(const int* __restrict__ ei, int* __restrict__ ofs,
                                                 const int* __restrict__ off,
                                                 const float2* __restrict__ as0v,
                                                 const float2* __restrict__ ad0v,
                                                 uint2* __restrict__ ew) {
  int t = blockIdx.x * 256 + threadIdx.x;
  if (t < N_EDGES) {
    int s = ei[t], d = ei[N_EDGES + t];
    float2 a_s = as0v[s], a_d = ad0v[d];
    float w0 = __expf(lrelu(a_s.x + a_d.x));
    float w1 = __expf(lrelu(a_s.y + a_d.y));
    int p = atomicAdd(&ofs[d], 1);
    ew[p] = make_uint2((uint)s, f2b(w0) | (f2b(w1) << 16));
  } else if (t < N_EDGES + N_NODES) {
    int n = t - N_EDGES;  // self-loop record in the reserved last slot
    int slot = off[n + 1] - 1;
    float2 a_s = as0v[n], a_d = ad0v[n];
    float w0 = __expf(lrelu(a_s.x + a_d.x));
    float w1 = __expf(lrelu(a_s.y + a_d.y));
    ew[slot] = make_uint2((uint)n, f2b(w0) | (f2b(w1) << 16));
  }
}

// ---------------- Fused aggregate L0 (+LN+ELU+linear1+alpha1) ----------------
// R14 = R10 structure (256 threads, 1 wave per node, 8/4/1 ILP ladder, VGPR~32-40)
// with ONE change: linear1 no longer uses 64x ds_bpermute + a 64-deep serial fma chain.
// y is staged once in a wave-private LDS row (no barrier) and read back as 16
// wave-uniform float4 broadcasts into 4 independent partial accumulators
// (serial chain 256cy -> ~64cy, DS ops 64 -> 17 per node).

__global__ __launch_bounds__(256) void k_agg0(const int* __restrict__ off,
                                              const uint2* __restrict__ ew,
                                              const uint* __restrict__ h0p,
                                              const float* __restrict__ b0,
                                              const float* __restrict__ lng,
                                              const float* __restrict__ lnb,
                                              const float* __restrict__ W1,
                                              const float* __restrict__ asrc1,
                                              const float* __restrict__ adst1,
                                              ushort* __restrict__ h1b,
                                              float* __restrict__ as1, float* __restrict__ ad1) {
  __shared__ float yb[4][64];  // wave-private y row for linear1 broadcasts
  int n = blockIdx.x * 4 + (threadIdx.x >> 6);
  int lane = threadIdx.x & 63;
  int wl = threadIdx.x >> 6;
  float acc0 = 0.f, acc1 = 0.f, den0 = 0.f, den1 = 0.f;
  int i0 = off[n], i1 = off[n + 1];
  int i = i0;
  for (; i + 7 < i1; i += 8) {
    uint2 r[8];
    uint h[8];
#pragma unroll
    for (int j = 0; j < 8; ++j) r[j] = ew[i + j];
#pragma unroll
    for (int j = 0; j < 8; ++j) h[j] = h0p[r[j].x * 64 + lane];
#pragma unroll
    for (int j = 0; j < 8; ++j) {
      float w;
      w = b2f_lo(r[j].y); acc0 += w * b2f_lo(h[j]); den0 += w;
      w = b2f_hi(r[j].y); acc1 += w * b2f_hi(h[j]); den1 += w;
    }
  }
  for (; i + 3 < i1; i += 4) {
    uint2 r[4];
    uint h[4];
#pragma unroll
    for (int j = 0; j < 4; ++j) r[j] = ew[i + j];
#pragma unroll
    for (int j = 0; j < 4; ++j) h[j] = h0p[r[j].x * 64 + lane];
#pragma unroll
    for (int j = 0; j < 4; ++j) {
      float w;
      w = b2f_lo(r[j].y); acc0 += w * b2f_lo(h[j]); den0 += w;
      w = b2f_hi(r[j].y); acc1 += w * b2f_hi(h[j]); den1 += w;
    }
  }
  for (; i < i1; ++i) {
    uint2 r = ew[i];
    uint h = h0p[r.x * 64 + lane];
    float w;
    w = b2f_lo(r.y); acc0 += w * b2f_lo(h); den0 += w;
    w = b2f_hi(r.y); acc1 += w * b2f_hi(h); den1 += w;
  }
  float v = 0.5f * (acc0 / den0 + acc1 / den1) + b0[lane];
  // LayerNorm across the 64 channels (one wave)
  float mu = v;
#pragma unroll
  for (int o = 32; o >= 1; o >>= 1) mu += __shfl_xor(mu, o, 64);
  mu *= (1.0f / 64.0f);
  float d = v - mu;
  float vr = d * d;
#pragma unroll
  for (int o = 32; o >= 1; o >>= 1) vr += __shfl_xor(vr, o, 64);
  vr *= (1.0f / 64.0f);
  float y = d * rsqrtf(vr + 1e-5f) * lng[lane] + lnb[lane];
  // ELU
  y = y > 0.f ? y : expm1f(y);
  // linear1 via LDS broadcast: h1[c] = sum_k y_k * W1[k,c], 4 partial accumulators.
  // yb row is wave-private: write then read by the same wave (compiler inserts lgkmcnt).
  yb[wl][lane] = y;
  const float4* yp = (const float4*)yb[wl];
  float p0 = 0.f, p1 = 0.f, p2 = 0.f, p3 = 0.f;
#pragma unroll
  for (int k4 = 0; k4 < 16; ++k4) {
    float4 yy = yp[k4];  // wave-uniform address -> LDS broadcast, conflict-free
    p0 = fmaf(yy.x, W1[(4 * k4 + 0) * 64 + lane], p0);
    p1 = fmaf(yy.y, W1[(4 * k4 + 1) * 64 + lane], p1);
    p2 = fmaf(yy.z, W1[(4 * k4 + 2) * 64 + lane], p2);
    p3 = fmaf(yy.w, W1[(4 * k4 + 3) * 64 + lane], p3);
  }
  float h1v = (p0 + p1) + (p2 + p3);
  h1b[n * 64 + lane] = (ushort)f2b(h1v);
  float sa = h1v * asrc1[lane];
  float sdv = h1v * adst1[lane];
#pragma unroll
  for (int o = 32; o >= 1; o >>= 1) {
    sa += __shfl_xor(sa, o, 64);
    sdv += __shfl_xor(sdv, o, 64);
  }
  if (lane == 0) {
    as1[n] = sa;
    ad1[n] = sdv;
  }
}

// ---------------- Layer 1 aggregate -> output (unchanged R10) ----------------

__global__ __launch_bounds__(256) void k_agg1(const int* __restrict__ off,
                                              const uint2* __restrict__ ew,
                                              const ushort* __restrict__ h1b,
                                              const float* __restrict__ as1,
                                              const float* __restrict__ ad1,
                                              const float* __restrict__ b1,
                                              float* __restrict__ out) {
  int n = blockIdx.x * 4 + (threadIdx.x >> 6);
  int lane = threadIdx.x & 63;
  float adv = ad1[n];
  float acc = 0.f, den = 0.f;
  int i0 = off[n], i1 = off[n + 1];
  int i = i0;
  for (; i + 7 < i1; i += 8) {
    uint s[8];
    float a[8];
    uint h[8];
#pragma unroll
    for (int j = 0; j < 8; ++j) s[j] = ew[i + j].x;
#pragma unroll
    for (int j = 0; j < 8; ++j) a[j] = as1[s[j]];
#pragma unroll
    for (int j = 0; j < 8; ++j) h[j] = h1b[s[j] * 64 + lane];
#pragma unroll
    for (int j = 0; j < 8; ++j) {
      float w = __expf(lrelu(a[j] + adv));
      acc += w * __uint_as_float(h[j] << 16);
      den += w;
    }
  }
  for (; i + 3 < i1; i += 4) {
    uint s[4];
    float a[4];
    uint h[4];
#pragma unroll
    for (int j = 0; j < 4; ++j) s[j] = ew[i + j].x;
#pragma unroll
    for (int j = 0; j < 4; ++j) a[j] = as1[s[j]];
#pragma unroll
    for (int j = 0; j < 4; ++j) h[j] = h1b[s[j] * 64 + lane];
#pragma unroll
    for (int j = 0; j < 4; ++j) {
      float w = __expf(lrelu(a[j] + adv));
      acc += w * __uint_as_float(h[j] << 16);
      den += w;
    }
  }
  for (; i < i1; ++i) {
    uint s = ew[i].x;
    float w = __expf(lrelu(as1[s] + adv));
    acc += w * __uint_as_float((uint)h1b[s * 64 + lane] << 16);
    den += w;
  }
  out[n * 64 + lane] = acc / den + b1[lane];
}

// ---------------- host ----------------

extern "C" void kernel_launch(void* const* d_in, const int* in_sizes, int n_in,
                              void* d_out, int out_size, void* d_ws, size_t ws_size,
                              hipStream_t stream) {
  const float* x    = (const float*)d_in[0];
  const int*   ei   = (const int*)d_in[1];
  const float* emb  = (const float*)d_in[2];
  const float* W0   = (const float*)d_in[3];
  const float* as0w = (const float*)d_in[4];
  const float* ad0w = (const float*)d_in[5];
  const float* b0   = (const float*)d_in[6];
  const float* lng  = (const float*)d_in[7];
  const float* lnb  = (const float*)d_in[8];
  const float* W1   = (const float*)d_in[9];
  const float* as1w = (const float*)d_in[10];
  const float* ad1w = (const float*)d_in[11];
  const float* b1   = (const float*)d_in[12];
  float* out = (float*)d_out;

  // workspace layout (8B-aligned arrays first); total ~29 MB
  uint2* ew  = (uint2*)d_ws;                  // E_TOT {src, bf16x2 w0|w1}
  float* as0 = (float*)(ew + E_TOT);          // N*2
  float* ad0 = as0 + N_NODES * 2;             // N*2
  float* as1 = ad0 + N_NODES * 2;             // N
  float* ad1 = as1 + N_NODES;                 // N
  uint* h0p = (uint*)(ad1 + N_NODES);         // N*64 (bf16x2 packed; written as ushort halves)
  ushort* h1b = (ushort*)(h0p + N_NODES * 64);  // N*64 bf16
  int* deg  = (int*)(h1b + N_NODES * 64);     // N
  int* off  = deg + N_NODES;                  // N+1
  int* ofs  = off + N_NODES + 1;              // N
  int* bsum = ofs + N_NODES;                  // 64

  hipMemsetAsync(deg, 0, N_NODES * sizeof(int), stream);
  k_node0h<<<NODE0_BLOCKS + HIST_BLOCKS, 256, 0, stream>>>(x, emb, W0, as0w, ad0w, ei,
                                                           (ushort*)h0p, as0, ad0, deg);
  k_scan1<<<SCAN_BLOCKS, 1024, 0, stream>>>(deg, off, bsum);
  k_scan23<<<SCAN_BLOCKS, 1024, 0, stream>>>(off, ofs, bsum);
  k_scatter<<<(N_EDGES + N_NODES + 255) / 256, 256, 0, stream>>>(ei, ofs, off, (const float2*)as0,
                                                                 (const float2*)ad0, ew);
  k_agg0<<<N_NODES / 4, 256, 0, stream>>>(off, ew, h0p, b0, lng, lnb, W1, as1w, ad1w,
                                          h1b, as1, ad1);
  k_agg1<<<N_NODES / 4, 256, 0, stream>>>(off, ew, h1b, as1, ad1, b1, out);
}

// Round 5
// 268.386 us; speedup vs baseline: 1.3118x; 1.0293x over previous
//
#include <hip/hip_runtime.h>
#include <hip/hip_bf16.h>

#define N_NODES 50000
#define N_EDGES 800000
#define E_TOT 850000  // edges + self loops, CSR-resident
#define F_IN 32
#define CELL_DIM 16
#define D_IN 48      // F_IN + CELL_DIM
#define X_STRIDE 33  // F_IN + 1 (cell id column)
#define NUM_CELLS 854
#define NEG_SLOPE 0.2f
#define SCAN_BLOCKS 49     // ceil(50000/1024)
#define NODE0_BLOCKS 2048  // persistent node0 blocks (8 nodes per block-iteration)
#define HIST_BLOCKS 3125   // ceil(800000/256)

typedef unsigned int uint;
typedef unsigned short ushort;

// f32 -> bf16 bits, round-to-nearest-even
static __device__ __forceinline__ uint f2b(float f) {
  uint x = __float_as_uint(f);
  return (x + 0x7fffu + ((x >> 16) & 1u)) >> 16;
}
static __device__ __forceinline__ float b2f_lo(uint w) { return __uint_as_float(w << 16); }
static __device__ __forceinline__ float b2f_hi(uint w) { return __uint_as_float(w & 0xffff0000u); }
static __device__ __forceinline__ float lrelu(float e) { return e > 0.f ? e : NEG_SLOPE * e; }

// ---------------- Fused node0 + degree histogram (unchanged, known-good) ----------------

__global__ __launch_bounds__(256) void k_node0h(const float* __restrict__ x,
                                                const float* __restrict__ emb,
                                                const float* __restrict__ W0,
                                                const float* __restrict__ asrc,
                                                const float* __restrict__ adst,
                                                const int* __restrict__ ei,
                                                ushort* __restrict__ h0u,
                                                float* __restrict__ as0, float* __restrict__ ad0,
                                                int* __restrict__ deg) {
  int tid = threadIdx.x;
  if (blockIdx.x >= NODE0_BLOCKS) {  // histogram part
    int e = (blockIdx.x - NODE0_BLOCKS) * 256 + tid;
    if (e < N_EDGES) atomicAdd(&deg[ei[N_EDGES + e]], 1);
    return;
  }
  __shared__ float hin[8][48];  // 8 node rows; float4 reads are wave-uniform (broadcast)
  int lane = tid & 63, wid = tid >> 6;
  int h = wid & 1;       // head
  int q = wid >> 1;      // node-quad (0: nodes 0-3, 1: nodes 4-7)
  float w0r[D_IN];       // 48 VGPRs: this head's W0 column for channel `lane`
#pragma unroll
  for (int k = 0; k < D_IN; ++k) w0r[k] = W0[k * 128 + h * 64 + lane];
  float av_s = asrc[h * 64 + lane], av_d = adst[h * 64 + lane];

  for (int g = blockIdx.x; g < N_NODES / 8; g += NODE0_BLOCKS) {
    int nb = g * 8;
    // stage: wave w stages rows 2w, 2w+1
#pragma unroll
    for (int j = 0; j < 2; ++j) {
      int loc = 2 * wid + j;
      int n = nb + loc;
      float t = 0.f;
      if (lane < 33) t = x[n * X_STRIDE + lane];
      int cid = (int)__shfl(t, 32, 64);
      cid = cid < 0 ? 0 : (cid >= NUM_CELLS ? NUM_CELLS - 1 : cid);  // fault guard
      if (lane >= 32 && lane < 48) t = emb[cid * CELL_DIM + (lane - 32)];
      if (lane < 48) hin[loc][lane] = t;
    }
    __syncthreads();
    // compute: 4 nodes of my quad, my head, channel = lane
#pragma unroll
    for (int j = 0; j < 4; ++j) {
      int loc = 4 * q + j;
      int n = nb + loc;
      const float4* hp = (const float4*)hin[loc];
      float acc = 0.f;
#pragma unroll
      for (int k4 = 0; k4 < 12; ++k4) {
        float4 hh = hp[k4];
        acc = fmaf(hh.x, w0r[4 * k4 + 0], acc);
        acc = fmaf(hh.y, w0r[4 * k4 + 1], acc);
        acc = fmaf(hh.z, w0r[4 * k4 + 2], acc);
        acc = fmaf(hh.w, w0r[4 * k4 + 3], acc);
      }
      h0u[(n * 64 + lane) * 2 + h] = (ushort)f2b(acc);  // packed half of the bf16x2 word
      float sa = acc * av_s, sd = acc * av_d;
#pragma unroll
      for (int o = 32; o >= 1; o >>= 1) {
        sa += __shfl_xor(sa, o, 64);
        sd += __shfl_xor(sd, o, 64);
      }
      if (lane == 0) {
        as0[n * 2 + h] = sa;
        ad0[n * 2 + h] = sd;
      }
    }
    __syncthreads();  // before restaging
  }
}

// ---------------- CSR scans (unchanged) ----------------

__global__ __launch_bounds__(1024) void k_scan1(const int* __restrict__ deg, int* __restrict__ off,
                                                int* __restrict__ bsum) {
  __shared__ int ws[16];
  int tid = threadIdx.x;
  int lane = tid & 63, wid = tid >> 6;
  int i = blockIdx.x * 1024 + tid;
  int v = (i < N_NODES) ? deg[i] + 1 : 0;  // +1 slot for self-loop
  int sc = v;
#pragma unroll
  for (int o = 1; o < 64; o <<= 1) {
    int t = __shfl_up(sc, o, 64);
    if (lane >= o) sc += t;
  }
  if (lane == 63) ws[wid] = sc;
  __syncthreads();
  if (tid < 16) {
    int w = ws[tid];
    int s = w;
#pragma unroll
    for (int o = 1; o < 16; o <<= 1) {
      int t = __shfl_up(s, o, 64);
      if (tid >= o) s += t;
    }
    ws[tid] = s - w;  // exclusive wave prefix
  }
  __syncthreads();
  int excl = sc - v + ws[wid];
  if (i < N_NODES) off[i] = excl;
  if (tid == 1023) bsum[blockIdx.x] = excl + v;  // block total
}

__global__ __launch_bounds__(1024) void k_scan23(int* __restrict__ off, int* __restrict__ ofs,
                                                 const int* __restrict__ bsum) {
  __shared__ int carry_s;
  int tid = threadIdx.x;
  if (tid < 64) {
    int v = (tid < SCAN_BLOCKS) ? bsum[tid] : 0;
    int s = v;
#pragma unroll
    for (int o = 1; o < 64; o <<= 1) {
      int t = __shfl_up(s, o, 64);
      if (tid >= o) s += t;
    }
    if (tid == (int)blockIdx.x) carry_s = s - v;  // exclusive prefix of this block
  }
  __syncthreads();
  int carry = carry_s;
  int i = blockIdx.x * 1024 + tid;
  if (i < N_NODES) {
    int v = off[i] + carry;
    off[i] = v;
    ofs[i] = v;
  }
  if (i == 0) off[N_NODES] = E_TOT;
}

// scatter edges into CSR slots + compute layer-0 attention weights (unchanged)
__global__ __launch_bounds__(256) void k_scatter(const int* __restrict__ ei, int* __restrict__ ofs,
                                                 const int* __restrict__ off,
                                                 const float2* __restrict__ as0v,
                                                 const float2* __restrict__ ad0v,
                                                 uint2* __restrict__ ew) {
  int t = blockIdx.x * 256 + threadIdx.x;
  if (t < N_EDGES) {
    int s = ei[t], d = ei[N_EDGES + t];
    float2 a_s = as0v[s], a_d = ad0v[d];
    float w0 = __expf(lrelu(a_s.x + a_d.x));
    float w1 = __expf(lrelu(a_s.y + a_d.y));
    int p = atomicAdd(&ofs[d], 1);
    ew[p] = make_uint2((uint)s, f2b(w0) | (f2b(w1) << 16));
  } else if (t < N_EDGES + N_NODES) {
    int n = t - N_EDGES;  // self-loop record in the reserved last slot
    int slot = off[n + 1] - 1;
    float2 a_s = as0v[n], a_d = ad0v[n];
    float w0 = __expf(lrelu(a_s.x + a_d.x));
    float w1 = __expf(lrelu(a_s.y + a_d.y));
    ew[slot] = make_uint2((uint)n, f2b(w0) | (f2b(w1) << 16));
  }
}

// ---------------- Fused aggregate L0 (+LN+ELU+linear1+alpha1) ----------------
// R15: predicated 8-wide ladder ONLY — nb = ceil(deg/8) batches, all 8-wide, last batch
// masked per-edge ((base+j<i1) ? : 0). Kills the 4-batch and the serial singles tail:
// dependent record->gather rounds per node drop ~3.5 -> ~2.25 at the R10-proven register
// footprint (r[8]+h[8], VGPR~40 -> no R11 occupancy cliff). Over-read past i1 stays inside
// the workspace (as0 follows ew); padded weights forced to exactly 0 (den>0 via self-loop);
// padded gathers redirect to h0p row 0 (L1-hot line). Epilogue = R14 (LDS-broadcast linear1).

__global__ __launch_bounds__(256) void k_agg0(const int* __restrict__ off,
                                              const uint2* __restrict__ ew,
                                              const uint* __restrict__ h0p,
                                              const float* __restrict__ b0,
                                              const float* __restrict__ lng,
                                              const float* __restrict__ lnb,
                                              const float* __restrict__ W1,
                                              const float* __restrict__ asrc1,
                                              const float* __restrict__ adst1,
                                              ushort* __restrict__ h1b,
                                              float* __restrict__ as1, float* __restrict__ ad1) {
  __shared__ float yb[4][64];  // wave-private y row for linear1 broadcasts
  int n = blockIdx.x * 4 + (threadIdx.x >> 6);
  int lane = threadIdx.x & 63;
  int wl = threadIdx.x >> 6;
  float acc0 = 0.f, acc1 = 0.f, den0 = 0.f, den1 = 0.f;
  int i0 = off[n], i1 = off[n + 1];
  int nbt = (i1 - i0 + 7) >> 3;  // >= 1 (self-loop guarantees i1 > i0)
  for (int b = 0; b < nbt; ++b) {
    int base = i0 + b * 8;
    uint2 r[8];
    uint h[8];
#pragma unroll
    for (int j = 0; j < 8; ++j) r[j] = ew[base + j];  // tail overrun lands in as0: valid mem
#pragma unroll
    for (int j = 0; j < 8; ++j) {
      uint sx = (base + j < i1) ? r[j].x : 0u;  // cndmask; pad -> row 0 (L1-hot)
      h[j] = h0p[sx * 64 + lane];
    }
#pragma unroll
    for (int j = 0; j < 8; ++j) {
      uint wy = (base + j < i1) ? r[j].y : 0u;  // cndmask; pad weight exactly 0
      float w;
      w = b2f_lo(wy); acc0 += w * b2f_lo(h[j]); den0 += w;
      w = b2f_hi(wy); acc1 += w * b2f_hi(h[j]); den1 += w;
    }
  }
  float v = 0.5f * (acc0 / den0 + acc1 / den1) + b0[lane];
  // LayerNorm across the 64 channels (one wave)
  float mu = v;
#pragma unroll
  for (int o = 32; o >= 1; o >>= 1) mu += __shfl_xor(mu, o, 64);
  mu *= (1.0f / 64.0f);
  float d = v - mu;
  float vr = d * d;
#pragma unroll
  for (int o = 32; o >= 1; o >>= 1) vr += __shfl_xor(vr, o, 64);
  vr *= (1.0f / 64.0f);
  float y = d * rsqrtf(vr + 1e-5f) * lng[lane] + lnb[lane];
  // ELU
  y = y > 0.f ? y : expm1f(y);
  // linear1 via LDS broadcast: h1[c] = sum_k y_k * W1[k,c], 4 partial accumulators.
  yb[wl][lane] = y;
  const float4* yp = (const float4*)yb[wl];
  float p0 = 0.f, p1 = 0.f, p2 = 0.f, p3 = 0.f;
#pragma unroll
  for (int k4 = 0; k4 < 16; ++k4) {
    float4 yy = yp[k4];  // wave-uniform address -> LDS broadcast, conflict-free
    p0 = fmaf(yy.x, W1[(4 * k4 + 0) * 64 + lane], p0);
    p1 = fmaf(yy.y, W1[(4 * k4 + 1) * 64 + lane], p1);
    p2 = fmaf(yy.z, W1[(4 * k4 + 2) * 64 + lane], p2);
    p3 = fmaf(yy.w, W1[(4 * k4 + 3) * 64 + lane], p3);
  }
  float h1v = (p0 + p1) + (p2 + p3);
  h1b[n * 64 + lane] = (ushort)f2b(h1v);
  float sa = h1v * asrc1[lane];
  float sdv = h1v * adst1[lane];
#pragma unroll
  for (int o = 32; o >= 1; o >>= 1) {
    sa += __shfl_xor(sa, o, 64);
    sdv += __shfl_xor(sdv, o, 64);
  }
  if (lane == 0) {
    as1[n] = sa;
    ad1[n] = sdv;
  }
}

// ---------------- Layer 1 aggregate -> output ----------------
// R15: same predicated 8-wide ladder (records loaded .x-only as in R10).

__global__ __launch_bounds__(256) void k_agg1(const int* __restrict__ off,
                                              const uint2* __restrict__ ew,
                                              const ushort* __restrict__ h1b,
                                              const float* __restrict__ as1,
                                              const float* __restrict__ ad1,
                                              const float* __restrict__ b1,
                                              float* __restrict__ out) {
  int n = blockIdx.x * 4 + (threadIdx.x >> 6);
  int lane = threadIdx.x & 63;
  float adv = ad1[n];
  float acc = 0.f, den = 0.f;
  int i0 = off[n], i1 = off[n + 1];
  int nbt = (i1 - i0 + 7) >> 3;
  for (int b = 0; b < nbt; ++b) {
    int base = i0 + b * 8;
    uint s[8];
    float a[8];
    uint h[8];
#pragma unroll
    for (int j = 0; j < 8; ++j) {
      uint sx = ew[base + j].x;                 // tail overrun: valid mem (as0 region)
      s[j] = (base + j < i1) ? sx : 0u;         // cndmask; pad -> node 0 (hot lines)
    }
#pragma unroll
    for (int j = 0; j < 8; ++j) a[j] = as1[s[j]];
#pragma unroll
    for (int j = 0; j < 8; ++j) h[j] = h1b[s[j] * 64 + lane];
#pragma unroll
    for (int j = 0; j < 8; ++j) {
      float w = __expf(lrelu(a[j] + adv));
      w = (base + j < i1) ? w : 0.f;            // pad weight exactly 0
      acc += w * __uint_as_float(h[j] << 16);
      den += w;
    }
  }
  out[n * 64 + lane] = acc / den + b1[lane];
}

// ---------------- host ----------------

extern "C" void kernel_launch(void* const* d_in, const int* in_sizes, int n_in,
                              void* d_out, int out_size, void* d_ws, size_t ws_size,
                              hipStream_t stream) {
  const float* x    = (const float*)d_in[0];
  const int*   ei   = (const int*)d_in[1];
  const float* emb  = (const float*)d_in[2];
  const float* W0   = (const float*)d_in[3];
  const float* as0w = (const float*)d_in[4];
  const float* ad0w = (const float*)d_in[5];
  const float* b0   = (const float*)d_in[6];
  const float* lng  = (const float*)d_in[7];
  const float* lnb  = (const float*)d_in[8];
  const float* W1   = (const float*)d_in[9];
  const float* as1w = (const float*)d_in[10];
  const float* ad1w = (const float*)d_in[11];
  const float* b1   = (const float*)d_in[12];
  float* out = (float*)d_out;

  // workspace layout (8B-aligned arrays first); total ~29 MB
  uint2* ew  = (uint2*)d_ws;                  // E_TOT {src, bf16x2 w0|w1}
  float* as0 = (float*)(ew + E_TOT);          // N*2
  float* ad0 = as0 + N_NODES * 2;             // N*2
  float* as1 = ad0 + N_NODES * 2;             // N
  float* ad1 = as1 + N_NODES;                 // N
  uint* h0p = (uint*)(ad1 + N_NODES);         // N*64 (bf16x2 packed; written as ushort halves)
  ushort* h1b = (ushort*)(h0p + N_NODES * 64);  // N*64 bf16
  int* deg  = (int*)(h1b + N_NODES * 64);     // N
  int* off  = deg + N_NODES;                  // N+1
  int* ofs  = off + N_NODES + 1;              // N
  int* bsum = ofs + N_NODES;                  // 64

  hipMemsetAsync(deg, 0, N_NODES * sizeof(int), stream);
  k_node0h<<<NODE0_BLOCKS + HIST_BLOCKS, 256, 0, stream>>>(x, emb, W0, as0w, ad0w, ei,
                                                           (ushort*)h0p, as0, ad0, deg);
  k_scan1<<<SCAN_BLOCKS, 1024, 0, stream>>>(deg, off, bsum);
  k_scan23<<<SCAN_BLOCKS, 1024, 0, stream>>>(off, ofs, bsum);
  k_scatter<<<(N_EDGES + N_NODES + 255) / 256, 256, 0, stream>>>(ei, ofs, off, (const float2*)as0,
                                                                 (const float2*)ad0, ew);
  k_agg0<<<N_NODES / 4, 256, 0, stream>>>(off, ew, h0p, b0, lng, lnb, W1, as1w, ad1w,
                                          h1b, as1, ad1);
  k_agg1<<<N_NODES / 4, 256, 0, stream>>>(off, ew, h1b, as1, ad1, b1, out);
}